// Round 2
// baseline (206.724 us; speedup 1.0000x reference)
//
#include <hip/hip_runtime.h>

// Problem constants (from reference setup_inputs) — all tensors are fp32.
#define BATCH 16
#define NVEC 1024
#define NDIM 64
#define NHID 32
#define NW   10
#define NCLS 10
#define NOFF 11      // diag + 10 power-of-2 offsets (chord mask: 11 nnz/row)

// ---------------------------------------------------------------------------
// Kernel 1: compute all sparse W entries for all 10 layers in parallel.
// h[b,n,:] = gelu(data[b,n,:] @ fW1[i] + fb1[i])   (data = ORIGINAL input;
//   h does not depend on V, so all layers are computable up front)
// Wsp[i][b][o][n] = h[b,n,:] . fW2[i][:, m_o] + fb2[i][m_o], m_o=(n+off_o)%1024
// Stored transposed [o][n] so writes coalesce over n and k_layer reads
// broadcast per row.
// grid: (NVEC/256, BATCH, NW), block 256 (one thread per row n)
// ---------------------------------------------------------------------------
__global__ __launch_bounds__(256) void k_weights(
    const float* __restrict__ data,   // [B][NVEC][NDIM]
    const float* __restrict__ fW1,    // [NW][NDIM][NHID]
    const float* __restrict__ fb1,    // [NW][NHID]
    const float* __restrict__ fW2,    // [NW][NHID][NVEC]
    const float* __restrict__ fb2,    // [NW][NVEC]
    float* __restrict__ Wsp)          // [NW][B][NOFF][NVEC]
{
    const int i = blockIdx.z;
    const int b = blockIdx.y;
    const int n = blockIdx.x * 256 + threadIdx.x;

    __shared__ float sW1[NDIM * NHID];
    __shared__ float sb1[NHID];
    {
        const float* w1 = fW1 + i * NDIM * NHID;
        for (int t = threadIdx.x; t < NDIM * NHID; t += 256) sW1[t] = w1[t];
        if (threadIdx.x < NHID) sb1[threadIdx.x] = fb1[i * NHID + threadIdx.x];
    }
    __syncthreads();

    // load this row of data (64 floats = 256B, aligned) via float4
    float d[NDIM];
    const float4* dv = (const float4*)(data + ((size_t)(b * NVEC) + n) * NDIM);
    #pragma unroll
    for (int q = 0; q < 16; ++q) {
        float4 u = dv[q];
        d[q * 4 + 0] = u.x; d[q * 4 + 1] = u.y;
        d[q * 4 + 2] = u.z; d[q * 4 + 3] = u.w;
    }

    // h = gelu(d @ W1 + b1), exact gelu (erf)
    float h[NHID];
    #pragma unroll
    for (int j = 0; j < NHID; ++j) h[j] = sb1[j];
    #pragma unroll 8
    for (int dd = 0; dd < NDIM; ++dd) {
        float x = d[dd];
        #pragma unroll
        for (int j = 0; j < NHID; ++j) h[j] += x * sW1[dd * NHID + j];
    }
    #pragma unroll
    for (int j = 0; j < NHID; ++j) {
        float x = h[j];
        h[j] = 0.5f * x * (1.0f + erff(x * 0.70710678118654752f));
    }

    // 11 sparse columns m_o = (n + off_o) % NVEC
    int m[NOFF];
    #pragma unroll
    for (int o = 0; o < NOFF; ++o) {
        int off = (o == 0) ? 0 : (1 << (o - 1));
        m[o] = (n + off) & (NVEC - 1);
    }
    float w[NOFF];
    const float* b2 = fb2 + i * NVEC;
    #pragma unroll
    for (int o = 0; o < NOFF; ++o) w[o] = b2[m[o]];

    const float* w2 = fW2 + (size_t)i * NHID * NVEC;
    #pragma unroll 4
    for (int j = 0; j < NHID; ++j) {
        float hj = h[j];
        const float* w2r = w2 + j * NVEC;
        #pragma unroll
        for (int o = 0; o < NOFF; ++o) w[o] += hj * w2r[m[o]];
    }

    // transposed store: coalesced over n
    float* wout = Wsp + ((size_t)(i * BATCH + b) * NOFF) * NVEC + n;
    #pragma unroll
    for (int o = 0; o < NOFF; ++o) wout[o * NVEC] = w[o];
}

// ---------------------------------------------------------------------------
// Kernel 2 (x10, sequential): Vout[b,n,:] = Vin[b,n,:] + sum_o w_o*Vin[b,m_o,:]
// grid: (NVEC/4, BATCH), block 256 = 4 rows x 64 dims
// ---------------------------------------------------------------------------
__global__ __launch_bounds__(256) void k_layer(
    const float* __restrict__ Vin, float* __restrict__ Vout,
    const float* __restrict__ Wsp, int layer)
{
    const int b  = blockIdx.y;
    const int n  = blockIdx.x * 4 + (threadIdx.x >> 6);
    const int dd = threadIdx.x & 63;
    const float* wb = Wsp + ((size_t)(layer * BATCH + b) * NOFF) * NVEC + n;
    const float* vb = Vin + (size_t)b * NVEC * NDIM;

    float acc = vb[n * NDIM + dd];   // residual
    #pragma unroll
    for (int o = 0; o < NOFF; ++o) {
        int off = (o == 0) ? 0 : (1 << (o - 1));
        int mm = (n + off) & (NVEC - 1);
        acc += wb[o * NVEC] * vb[mm * NDIM + dd];
    }
    Vout[((size_t)b * NVEC + n) * NDIM + dd] = acc;
}

// ---------------------------------------------------------------------------
// Kernel 3: split-K partials of flat @ final_W. grid: (16 k-chunks, BATCH)
// ---------------------------------------------------------------------------
__global__ __launch_bounds__(256) void k_final_partial(
    const float* __restrict__ V, const float* __restrict__ Wf,
    float* __restrict__ part)
{
    const int b = blockIdx.y;
    const int chunk = blockIdx.x;
    float acc[NCLS];
    #pragma unroll
    for (int c = 0; c < NCLS; ++c) acc[c] = 0.0f;

    const float* vb = V + (size_t)b * NVEC * NDIM;
    int k0 = chunk * 4096 + threadIdx.x;
    for (int it = 0; it < 16; ++it) {
        int k = k0 + it * 256;
        float v = vb[k];
        const float2* wr = (const float2*)(Wf + (size_t)k * NCLS);  // 40B stride, 8B aligned
        #pragma unroll
        for (int p = 0; p < 5; ++p) {
            float2 u = wr[p];
            acc[p * 2]     += v * u.x;
            acc[p * 2 + 1] += v * u.y;
        }
    }

    __shared__ float red[256];
    for (int c = 0; c < NCLS; ++c) {
        red[threadIdx.x] = acc[c];
        __syncthreads();
        for (int s = 128; s > 0; s >>= 1) {
            if (threadIdx.x < s) red[threadIdx.x] += red[threadIdx.x + s];
            __syncthreads();
        }
        if (threadIdx.x == 0) part[((size_t)b * NCLS + c) * 16 + chunk] = red[0];
        __syncthreads();
    }
}

__global__ __launch_bounds__(256) void k_finish(
    const float* __restrict__ part, const float* __restrict__ bias,
    float* __restrict__ out)
{
    int t = threadIdx.x;
    if (t < BATCH * NCLS) {
        int c = t % NCLS;
        float s = bias[c];
        #pragma unroll
        for (int ch = 0; ch < 16; ++ch) s += part[(size_t)t * 16 + ch];
        out[t] = s;
    }
}

// ---------------------------------------------------------------------------
extern "C" void kernel_launch(void* const* d_in, const int* in_sizes, int n_in,
                              void* d_out, int out_size, void* d_ws, size_t ws_size,
                              hipStream_t stream) {
    const float* data = (const float*)d_in[0];
    const float* fW1  = (const float*)d_in[1];
    const float* fb1  = (const float*)d_in[2];
    const float* fW2  = (const float*)d_in[3];
    const float* fb2  = (const float*)d_in[4];
    const float* fWf  = (const float*)d_in[5];
    const float* fbf  = (const float*)d_in[6];
    float* out = (float*)d_out;

    float* ws  = (float*)d_ws;
    float* V0  = ws;                      // 1,048,576 floats (4 MB)
    float* V1  = ws + (1 << 20);          // 1,048,576 floats (4 MB)
    float* Wsp = ws + (2 << 20);          // NW*B*NOFF*NVEC = 1,802,240 floats (7.2 MB)
    float* part = Wsp + (size_t)NW * BATCH * NOFF * NVEC;  // 2,560 floats

    // all sparse weights, all layers, in parallel (h depends only on data)
    k_weights<<<dim3(NVEC / 256, BATCH, NW), 256, 0, stream>>>(
        data, fW1, fb1, fW2, fb2, Wsp);

    // sequential sparse V-update chain, layers 9..0; first layer reads data
    const float* vin = data;
    float* bufs[2] = { V1, V0 };
    for (int l = 0; l < NW; ++l) {
        float* vout = bufs[l & 1];
        k_layer<<<dim3(NVEC / 4, BATCH), 256, 0, stream>>>(vin, vout, Wsp, NW - 1 - l);
        vin = vout;
    }

    // final projection [16,65536] @ [65536,10] + b
    k_final_partial<<<dim3(16, BATCH), 256, 0, stream>>>(vin, fWf, part);
    k_finish<<<dim3(1), 256, 0, stream>>>(part, fbf, out);
}

// Round 3
// 131.592 us; speedup vs baseline: 1.5709x; 1.5709x over previous
//
#include <hip/hip_runtime.h>

// Problem constants (from reference setup_inputs) — all tensors are fp32.
#define BATCH 16
#define NVEC 1024
#define NDIM 64
#define NHID 32
#define NW   10
#define NCLS 10
#define NOFF 11      // diag + 10 power-of-2 offsets (chord mask: 11 nnz/row)
#define DCH  4       // dims per fused-chain block (float4 granularity)

// ---------------------------------------------------------------------------
// Kernel 1: all sparse W entries for all 10 layers in parallel.
// h[b,n,:] = gelu(data[b,n,:] @ fW1[i] + fb1[i])  (h depends only on data)
// Wsp[i][b][o][n] = h . fW2[i][:, (n+off_o)%1024] + fb2[i][(n+off_o)%1024]
// No d[64] array: stream data float4-at-a-time into h accumulators (the
// round-2 version spilled d[64] to scratch -> 41MB of bogus write traffic).
// grid (NVEC/256, BATCH, NW), block 256.
// ---------------------------------------------------------------------------
__global__ __launch_bounds__(256) void k_weights(
    const float* __restrict__ data,   // [B][NVEC][NDIM]
    const float* __restrict__ fW1,    // [NW][NDIM][NHID]
    const float* __restrict__ fb1,    // [NW][NHID]
    const float* __restrict__ fW2,    // [NW][NHID][NVEC]
    const float* __restrict__ fb2,    // [NW][NVEC]
    float* __restrict__ Wsp)          // [NW][B][NOFF][NVEC]
{
    const int i = blockIdx.z;
    const int b = blockIdx.y;
    const int n = blockIdx.x * 256 + threadIdx.x;

    __shared__ float4 sW1[NDIM * NHID / 4];   // [dd][jv], jv = j/4
    __shared__ float  sb1[NHID];
    {
        const float4* w1v = (const float4*)(fW1 + (size_t)i * NDIM * NHID);
        for (int t = threadIdx.x; t < NDIM * NHID / 4; t += 256) sW1[t] = w1v[t];
        if (threadIdx.x < NHID) sb1[threadIdx.x] = fb1[i * NHID + threadIdx.x];
    }
    __syncthreads();

    // h accumulators: 8 float4 = all 32 hidden units
    float4 h4[8];
    #pragma unroll
    for (int jv = 0; jv < 8; ++jv) {
        h4[jv].x = sb1[jv * 4 + 0]; h4[jv].y = sb1[jv * 4 + 1];
        h4[jv].z = sb1[jv * 4 + 2]; h4[jv].w = sb1[jv * 4 + 3];
    }

    const float4* dv = (const float4*)(data + ((size_t)(b * NVEC) + n) * NDIM);
    #pragma unroll
    for (int q = 0; q < 16; ++q) {
        float4 u = dv[q];
        float xs[4] = {u.x, u.y, u.z, u.w};
        #pragma unroll
        for (int p = 0; p < 4; ++p) {
            float x = xs[p];
            #pragma unroll
            for (int jv = 0; jv < 8; ++jv) {
                float4 wv = sW1[(q * 4 + p) * 8 + jv];
                h4[jv].x += x * wv.x; h4[jv].y += x * wv.y;
                h4[jv].z += x * wv.z; h4[jv].w += x * wv.w;
            }
        }
    }

    // exact gelu
    float* h = (float*)h4;
    #pragma unroll
    for (int j = 0; j < NHID; ++j) {
        float x = h[j];
        h[j] = 0.5f * x * (1.0f + erff(x * 0.70710678118654752f));
    }

    // 11 sparse columns m_o = (n + off_o) % NVEC
    int m[NOFF];
    #pragma unroll
    for (int o = 0; o < NOFF; ++o) {
        int off = (o == 0) ? 0 : (1 << (o - 1));
        m[o] = (n + off) & (NVEC - 1);
    }
    float w[NOFF];
    const float* b2 = fb2 + i * NVEC;
    #pragma unroll
    for (int o = 0; o < NOFF; ++o) w[o] = b2[m[o]];

    const float* w2 = fW2 + (size_t)i * NHID * NVEC;
    #pragma unroll 4
    for (int j = 0; j < NHID; ++j) {
        float hj = h[j];
        const float* w2r = w2 + j * NVEC;
        #pragma unroll
        for (int o = 0; o < NOFF; ++o) w[o] += hj * w2r[m[o]];
    }

    float* wout = Wsp + ((size_t)(i * BATCH + b) * NOFF) * NVEC + n;
    #pragma unroll
    for (int o = 0; o < NOFF; ++o) wout[o * NVEC] = w[o];
}

// ---------------------------------------------------------------------------
// Kernel 2: FUSED 10-layer chain + final-projection partials.
// Block = (b, 4-dim chunk). The chord gather mixes only across n, so the
// block's V[1024][4] slice is closed under the update -> keep it in LDS
// (float4 per n: every gather is one aligned ds_read_b128, lanes consecutive
// -> conflict-free). Double-buffered, 1 barrier/layer, 10 layers, then the
// final projection partial straight out of LDS. Thread t owns n = t+256c,
// c=0..3; offsets 256/512 reuse the thread's own off-0 reads.
// grid (16 chunks, 16 b), block 256.
// ---------------------------------------------------------------------------
__global__ __launch_bounds__(256) void k_chain(
    const float* __restrict__ data,   // [B][NVEC][NDIM]
    const float* __restrict__ Wsp,    // [NW][B][NOFF][NVEC]
    const float* __restrict__ Wf,     // [NVEC*NDIM][NCLS]
    float* __restrict__ part)         // [B][16][NCLS]
{
    const int chunk = blockIdx.x;
    const int b     = blockIdx.y;
    const int d0    = chunk * DCH;
    const int t     = threadIdx.x;

    __shared__ float4 bufA[NVEC];
    __shared__ float4 bufB[NVEC];

    // init: V0 = data[b, :, d0:d0+4]
    #pragma unroll
    for (int c = 0; c < 4; ++c) {
        int n = t + 256 * c;
        bufA[n] = *(const float4*)(data + ((size_t)(b * NVEC) + n) * NDIM + d0);
    }
    __syncthreads();

    float4* cur = bufA;
    float4* nxt = bufB;

    for (int l = 0; l < NW; ++l) {
        const int layer = NW - 1 - l;  // reference iterates layers in reverse
        const float* wb = Wsp + ((size_t)(layer * BATCH + b) * NOFF) * NVEC;

        float4 v0[4], acc[4];
        // o = 0: diagonal + residual  (acc = v0 + w0*v0)
        #pragma unroll
        for (int c = 0; c < 4; ++c) {
            int n = t + 256 * c;
            float w0 = wb[n];
            v0[c] = cur[n];
            acc[c].x = v0[c].x + w0 * v0[c].x;
            acc[c].y = v0[c].y + w0 * v0[c].y;
            acc[c].z = v0[c].z + w0 * v0[c].z;
            acc[c].w = v0[c].w + w0 * v0[c].w;
        }
        // o = 1..8: offsets 1,2,4,...,128 (gather from LDS)
        #pragma unroll
        for (int o = 1; o <= 8; ++o) {
            int off = 1 << (o - 1);
            const float* wo = wb + o * NVEC;
            #pragma unroll
            for (int c = 0; c < 4; ++c) {
                int n = t + 256 * c;
                float wv = wo[n];
                float4 vv = cur[(n + off) & (NVEC - 1)];
                acc[c].x += wv * vv.x; acc[c].y += wv * vv.y;
                acc[c].z += wv * vv.z; acc[c].w += wv * vv.w;
            }
        }
        // o = 9 (off 256) and o = 10 (off 512): reuse v0 of rotated c
        #pragma unroll
        for (int c = 0; c < 4; ++c) {
            int n = t + 256 * c;
            float w9  = wb[9 * NVEC + n];
            float w10 = wb[10 * NVEC + n];
            float4 a = v0[(c + 1) & 3];
            float4 bb = v0[(c + 2) & 3];
            acc[c].x += w9 * a.x + w10 * bb.x;
            acc[c].y += w9 * a.y + w10 * bb.y;
            acc[c].z += w9 * a.z + w10 * bb.z;
            acc[c].w += w9 * a.w + w10 * bb.w;
        }
        #pragma unroll
        for (int c = 0; c < 4; ++c) nxt[t + 256 * c] = acc[c];
        __syncthreads();
        float4* tmp = cur; cur = nxt; nxt = tmp;
    }

    // fused final projection partial: part[b][chunk][cls] over this d-chunk
    float p[NCLS];
    #pragma unroll
    for (int c = 0; c < NCLS; ++c) p[c] = 0.0f;
    #pragma unroll
    for (int c = 0; c < 4; ++c) {
        int n = t + 256 * c;
        float4 vv = cur[n];
        float vs[4] = {vv.x, vv.y, vv.z, vv.w};
        const float4* wfv = (const float4*)(Wf + ((size_t)(n * NDIM + d0)) * NCLS);
        float wf[40];
        #pragma unroll
        for (int k = 0; k < 10; ++k) {
            float4 u = wfv[k];
            wf[k * 4 + 0] = u.x; wf[k * 4 + 1] = u.y;
            wf[k * 4 + 2] = u.z; wf[k * 4 + 3] = u.w;
        }
        #pragma unroll
        for (int d = 0; d < 4; ++d)
            #pragma unroll
            for (int cls = 0; cls < NCLS; ++cls)
                p[cls] += vs[d] * wf[d * NCLS + cls];
    }

    // block reduce: wave shfl, then cross-wave via (dead) nxt buffer
    const int lane = t & 63, wv = t >> 6;
    float* sred = (float*)nxt;   // nxt holds layer-8 output: dead after last barrier
    #pragma unroll
    for (int cls = 0; cls < NCLS; ++cls) {
        float v = p[cls];
        #pragma unroll
        for (int s = 32; s > 0; s >>= 1) v += __shfl_down(v, s, 64);
        if (lane == 0) sred[wv * NCLS + cls] = v;
    }
    __syncthreads();
    if (t < NCLS) {
        float s = sred[t] + sred[NCLS + t] + sred[2 * NCLS + t] + sred[3 * NCLS + t];
        part[(size_t)(b * 16 + chunk) * NCLS + t] = s;
    }
}

// ---------------------------------------------------------------------------
__global__ __launch_bounds__(256) void k_finish(
    const float* __restrict__ part, const float* __restrict__ bias,
    float* __restrict__ out)
{
    int t = threadIdx.x;
    if (t < BATCH * NCLS) {
        int b = t / NCLS, cls = t % NCLS;
        float s = bias[cls];
        #pragma unroll
        for (int ch = 0; ch < 16; ++ch) s += part[(size_t)(b * 16 + ch) * NCLS + cls];
        out[t] = s;
    }
}

// ---------------------------------------------------------------------------
extern "C" void kernel_launch(void* const* d_in, const int* in_sizes, int n_in,
                              void* d_out, int out_size, void* d_ws, size_t ws_size,
                              hipStream_t stream) {
    const float* data = (const float*)d_in[0];
    const float* fW1  = (const float*)d_in[1];
    const float* fb1  = (const float*)d_in[2];
    const float* fW2  = (const float*)d_in[3];
    const float* fb2  = (const float*)d_in[4];
    const float* fWf  = (const float*)d_in[5];
    const float* fbf  = (const float*)d_in[6];
    float* out = (float*)d_out;

    float* ws   = (float*)d_ws;
    float* Wsp  = ws;                                        // 1,802,240 floats (7.2 MB)
    float* part = ws + (size_t)NW * BATCH * NOFF * NVEC;     // 2,560 floats

    k_weights<<<dim3(NVEC / 256, BATCH, NW), 256, 0, stream>>>(
        data, fW1, fb1, fW2, fb2, Wsp);
    k_chain<<<dim3(NDIM / DCH, BATCH), 256, 0, stream>>>(data, Wsp, fWf, part);
    k_finish<<<dim3(1), 256, 0, stream>>>(part, fbf, out);
}